// Round 9
// baseline (507.043 us; speedup 1.0000x reference)
//
#include <hip/hip_runtime.h>

// ---------------------------------------------------------------------------
// TransformerBlock on MI355X (gfx950), bf16 MFMA internal compute.
// B=4 T=2048 C=1024 H=16 D=64 FF=4096. All fp32 I/O; bf16 internally.
//
// R8: revert QKV/FF1 to the proven 128^2 GEMM (256^2 port underperformed
// twice: MfmaUtil 17%, ~570 TF vs 128^2's ~900 TF).  Attention:
//  - unpaired grid (16,16,4) = 1024 blocks -> 4 blocks/CU (was 2), 2x
//    latency hiding; dynamic scheduling absorbs causal imbalance.
//  - merged 64-key softmax: one max/exp2/sum/rescale pass per k-tile
//    (was per 32-key subtile) — halves softmax overhead per key.
// ---------------------------------------------------------------------------

#define DEVI __device__ __forceinline__

typedef float  f32x4  __attribute__((ext_vector_type(4)));
typedef float  f32x16 __attribute__((ext_vector_type(16)));
typedef __bf16 bf16x8 __attribute__((ext_vector_type(8)));
typedef short  s16x8  __attribute__((ext_vector_type(8)));
typedef unsigned int u32x4 __attribute__((ext_vector_type(4)));
typedef unsigned short u16;

DEVI u16 f2bf(float f) {            // native RNE fp32->bf16
    return __builtin_bit_cast(u16, (__bf16)f);
}

DEVI unsigned pk2(float lo, float hi2) {    // {bf16(lo), bf16(hi2)} dword
    return (unsigned)f2bf(lo) | ((unsigned)f2bf(hi2) << 16);
}

DEVI void gload_lds16(const void* g, void* l) {
    __builtin_amdgcn_global_load_lds(
        (__attribute__((address_space(1))) void*)(g),
        (__attribute__((address_space(3))) void*)(l), 16, 0, 0);
}

DEVI f32x4 mfma16(s16x8 a, s16x8 b, f32x4 c) {
    return __builtin_amdgcn_mfma_f32_16x16x32_bf16(
        __builtin_bit_cast(bf16x8, a), __builtin_bit_cast(bf16x8, b), c, 0, 0, 0);
}

DEVI f32x16 mfma32(s16x8 a, s16x8 b, f32x16 c) {
    return __builtin_amdgcn_mfma_f32_32x32x16_bf16(
        __builtin_bit_cast(bf16x8, a), __builtin_bit_cast(bf16x8, b), c, 0, 0, 0);
}

// ---------------------------------------------------------------------------
// Tiled transpose + fp32->bf16: dst[n][k] = src[k][n].  64x64 tile, 256 thr.
// ---------------------------------------------------------------------------
__global__ __launch_bounds__(256) void transpose_cvt(
    const float* __restrict__ src, u16* __restrict__ dst,
    int K, int N, long srcStride, long dstStride)
{
    __shared__ float t[64][65];
    src += (long)blockIdx.z * srcStride;
    dst += (long)blockIdx.z * dstStride;
    int k0 = blockIdx.x * 64, n0 = blockIdx.y * 64;
    int tx = threadIdx.x & 63, ty = threadIdx.x >> 6;
#pragma unroll
    for (int i = 0; i < 16; ++i) {
        int r = ty * 16 + i;
        t[r][tx] = src[(long)(k0 + r) * N + n0 + tx];
    }
    __syncthreads();
#pragma unroll
    for (int i = 0; i < 16; ++i) {
        int r = ty * 16 + i;
        dst[(long)(n0 + r) * K + k0 + tx] = f2bf(t[tx][r]);
    }
}

// ---------------------------------------------------------------------------
// LayerNorm row (C=1024) -> bf16.  1 row / block, 256 threads, float4 loads.
// ---------------------------------------------------------------------------
__global__ __launch_bounds__(256) void ln_bf16(
    const float* __restrict__ x, const float* __restrict__ g,
    const float* __restrict__ b, u16* __restrict__ out)
{
    int row = blockIdx.x, tid = threadIdx.x;
    const float4 v = ((const float4*)(x + (long)row * 1024))[tid];
    float s = v.x + v.y + v.z + v.w;
    float q = v.x * v.x + v.y * v.y + v.z * v.z + v.w * v.w;
#pragma unroll
    for (int m = 1; m < 64; m <<= 1) { s += __shfl_xor(s, m); q += __shfl_xor(q, m); }
    __shared__ float red[8];
    int lane = tid & 63, w = tid >> 6;
    if (lane == 0) { red[w] = s; red[w + 4] = q; }
    __syncthreads();
    s = red[0] + red[1] + red[2] + red[3];
    q = red[4] + red[5] + red[6] + red[7];
    float mu  = s * (1.0f / 1024.0f);
    float var = q * (1.0f / 1024.0f) - mu * mu;
    float rs  = rsqrtf(var + 1e-5f);
    float4 gv = ((const float4*)g)[tid];
    float4 bv = ((const float4*)b)[tid];
    ushort4 o;
    o.x = f2bf((v.x - mu) * rs * gv.x + bv.x);
    o.y = f2bf((v.y - mu) * rs * gv.y + bv.y);
    o.z = f2bf((v.z - mu) * rs * gv.z + bv.z);
    o.w = f2bf((v.w - mu) * rs * gv.w + bv.w);
    ((ushort4*)(out + (long)row * 1024))[tid] = o;
}

// ---------------------------------------------------------------------------
// GEMM: C[M,N] = A[M,K] * B[K,N], A row-major bf16, Bt = B^T [N][K] bf16.
// 128x128 tile, BK=32, 4 waves (2x2), 4x4 16x16x32 MFMA frags per wave.
// EPI: 0 = QKV scatter (V transposed!), 1 = +bias +resid -> fp32,
//      2 = relu(+bias) -> bf16
// ---------------------------------------------------------------------------
template <int EPI>
__global__ __launch_bounds__(256, 3) void gemm_bt(
    const u16* __restrict__ A, const u16* __restrict__ Bt,
    int M, int N, int K,
    float* __restrict__ outF, u16* __restrict__ outB,
    const float* __restrict__ bias, const float* __restrict__ resid,
    u16* __restrict__ qd, u16* __restrict__ kd, u16* __restrict__ vd)
{
    __shared__ alignas(16) u16 As[128 * 32];
    __shared__ alignas(16) u16 Bs[128 * 32];
    int tid = threadIdx.x;
    int lane = tid & 63, w = tid >> 6;
    int wm = w & 1, wn = w >> 1;
    int l15 = lane & 15, l4 = lane >> 4;
    long m0 = (long)blockIdx.x * 128, n0 = (long)blockIdx.y * 128;
    const u16* Ag = A + m0 * K;
    const u16* Bg = Bt + n0 * K;
    int scol = (lane & 3) * 8;
    int srow0 = (w * 2 + 0) * 16 + (lane >> 2);
    int srow1 = (w * 2 + 1) * 16 + (lane >> 2);

    f32x4 acc[4][4] = {};

    for (int kt = 0; kt < K; kt += 32) {
        gload_lds16(Ag + (long)srow0 * K + kt + scol, &As[(w * 2 + 0) * 512]);
        gload_lds16(Ag + (long)srow1 * K + kt + scol, &As[(w * 2 + 1) * 512]);
        gload_lds16(Bg + (long)srow0 * K + kt + scol, &Bs[(w * 2 + 0) * 512]);
        gload_lds16(Bg + (long)srow1 * K + kt + scol, &Bs[(w * 2 + 1) * 512]);
        __syncthreads();
        s16x8 a[4], b[4];
#pragma unroll
        for (int m = 0; m < 4; ++m)
            a[m] = *(const s16x8*)&As[(wm * 64 + m * 16 + l15) * 32 + l4 * 8];
#pragma unroll
        for (int n = 0; n < 4; ++n)
            b[n] = *(const s16x8*)&Bs[(wn * 64 + n * 16 + l15) * 32 + l4 * 8];
#pragma unroll
        for (int m = 0; m < 4; ++m)
#pragma unroll
            for (int n = 0; n < 4; ++n)
                acc[m][n] = mfma16(a[m], b[n], acc[m][n]);
        __syncthreads();
    }

    long mbase = m0 + wm * 64;
    long nbase = n0 + wn * 64;
#pragma unroll
    for (int m = 0; m < 4; ++m)
#pragma unroll
        for (int n = 0; n < 4; ++n)
#pragma unroll
            for (int r = 0; r < 4; ++r) {
                long row = mbase + m * 16 + l4 * 4 + r;
                long col = nbase + n * 16 + l15;
                float val = acc[m][n][r];
                if constexpr (EPI == 0) {
                    int c = (int)col;
                    int which = c >> 10, hh = (c >> 6) & 15, dd = c & 63;
                    int bb = (int)(row >> 11), tt = (int)(row & 2047);
                    if (which == 2) {
                        vd[((long)(bb * 16 + hh) * 64 + dd) * 2048 + tt] = f2bf(val);
                    } else {
                        u16* dst = which == 0 ? qd : kd;
                        dst[((long)(bb * 16 + hh) * 2048 + tt) * 64 + dd] = f2bf(val);
                    }
                } else if constexpr (EPI == 1) {
                    outF[row * N + col] = val + bias[col] + resid[row * N + col];
                } else {
                    float t2 = val + bias[col];
                    outB[row * N + col] = f2bf(t2 > 0.f ? t2 : 0.f);
                }
            }
}

// ---------------------------------------------------------------------------
// Causal flash attention, swapped-operand 32x32 MFMA.
// Block = (qt, h, b): ONE q-tile of 128 rows (4 waves x 32), 1024 blocks
// -> 4 blocks/CU.  Merged 64-key softmax per k-tile.
// S^T = mfma32(K,Q): lane l31 = q, regs = k (crow(r,hi)=(r&3)+8(r>>2)+4hi).
// P->A-frag: f2bf pack + shfl_xor(32) + select.  K [s][d], V^T [d][s] in
// LDS (PAD=72), double-buffered, reg-staged 2 tiles ahead.
// ---------------------------------------------------------------------------
__global__ __launch_bounds__(256, 4) void attn_kernel(
    const u16* __restrict__ Q, const u16* __restrict__ K,
    const u16* __restrict__ Vt, u16* __restrict__ O)
{
    constexpr int PAD = 72;
    constexpr float SC2 = 0.125f * 1.44269504088896f;   // scale * log2(e)
    constexpr float THR = 11.5416f;                     // 8 * log2(e)
    __shared__ alignas(16) u16 Ks[2][64 * PAD];
    __shared__ alignas(16) u16 Vts[2][64 * PAD];
    __shared__ alignas(16) float xbuf[4][32];           // per-wave bounce
    int tid = threadIdx.x, lane = tid & 63, w = tid >> 6;
    int l31 = lane & 31, hi = lane >> 5;
    bool h = (hi != 0);
    int qt = blockIdx.x, hh = blockIdx.y, bb = blockIdx.z;
    const long hbase = ((long)(bb * 16 + hh)) * 2048 * 64;

    int srow[2], scol8[2];
#pragma unroll
    for (int i = 0; i < 2; ++i) {
        int c = tid + 256 * i;
        srow[i] = c >> 3;
        scol8[i] = (c & 7) * 8;
    }

    int q0w = qt * 128 + w * 32;
    int nt = 2 * qt + 2;
    int qv = q0w + l31;                     // this lane's q row

    // Q b-frags: b[j] = Q[q0w+l31][c*16 + hi*8 + j]
    s16x8 bq[4];
#pragma unroll
    for (int c = 0; c < 4; ++c)
        bq[c] = *(const s16x8*)&Q[hbase + (long)(q0w + l31) * 64 + c * 16 + hi * 8];

    f32x16 o0 = {}, o1 = {};                // O[q=crow][d=l31 | 32+l31]
    float mrow = -1e30f, lrow = 0.f;

    // ---- prologue: tile0 -> buf0 (direct), tile1 -> regs ----
    s16x8 kr[2], vr[2];
    {
        const u16* Kg = K + hbase;
        const u16* Vg = Vt + hbase;
#pragma unroll
        for (int i = 0; i < 2; ++i) {
            s16x8 k0 = *(const s16x8*)&Kg[srow[i] * 64 + scol8[i]];
            s16x8 v0 = *(const s16x8*)&Vg[(long)srow[i] * 2048 + scol8[i]];
            *(s16x8*)&Ks[0][srow[i] * PAD + scol8[i]]  = k0;
            *(s16x8*)&Vts[0][srow[i] * PAD + scol8[i]] = v0;
        }
        if (nt > 1) {
            const u16* Kg1 = K + hbase + 64 * 64;
            const u16* Vg1 = Vt + hbase + 64;
#pragma unroll
            for (int i = 0; i < 2; ++i) {
                kr[i] = *(const s16x8*)&Kg1[srow[i] * 64 + scol8[i]];
                vr[i] = *(const s16x8*)&Vg1[(long)srow[i] * 2048 + scol8[i]];
            }
        }
    }
    __syncthreads();

#pragma unroll 1
    for (int kt = 0; kt < nt; ++kt) {
        int cur = kt & 1;
        if (kt + 1 < nt) {
#pragma unroll
            for (int i = 0; i < 2; ++i) {
                *(s16x8*)&Ks[cur ^ 1][srow[i] * PAD + scol8[i]]  = kr[i];
                *(s16x8*)&Vts[cur ^ 1][srow[i] * PAD + scol8[i]] = vr[i];
            }
        }
        if (kt + 2 < nt) {
            const u16* Kg = K + hbase + (long)(kt + 2) * 64 * 64;
            const u16* Vg = Vt + hbase + (long)(kt + 2) * 64;
#pragma unroll
            for (int i = 0; i < 2; ++i) {
                kr[i] = *(const s16x8*)&Kg[srow[i] * 64 + scol8[i]];
                vr[i] = *(const s16x8*)&Vg[(long)srow[i] * 2048 + scol8[i]];
            }
        }

        int kb0 = kt * 64;
        if (kb0 <= q0w + 31) {
            bool live1 = (kb0 + 32 <= q0w + 31);

            // --- S^T for both 32-key subtiles ---
            f32x16 s0 = {}, s1;
            __builtin_amdgcn_s_setprio(1);
#pragma unroll
            for (int c = 0; c < 4; ++c) {
                s16x8 ak = *(const s16x8*)&Ks[cur][(l31) * PAD + c * 16 + hi * 8];
                s0 = mfma32(ak, bq[c], s0);
            }
            __builtin_amdgcn_s_setprio(0);
            if (live1) {
                f32x16 z = {};
                __builtin_amdgcn_s_setprio(1);
#pragma unroll
                for (int c = 0; c < 4; ++c) {
                    s16x8 ak = *(const s16x8*)&Ks[cur][(32 + l31) * PAD + c * 16 + hi * 8];
                    z = mfma32(ak, bq[c], z);
                }
                __builtin_amdgcn_s_setprio(0);
                s1 = z;
            } else {
#pragma unroll
                for (int r = 0; r < 16; ++r) s1[r] = -1e30f;
            }

            // --- scale + causal mask ---
            int khi0 = kb0 + 4 * hi;
            if (kb0 + 31 > q0w) {
#pragma unroll
                for (int r = 0; r < 16; ++r) {
                    int kg = khi0 + ((r & 3) + 8 * (r >> 2));
                    s0[r] = (kg > qv) ? -1e30f : s0[r] * SC2;
                }
            } else {
#pragma unroll
                for (int r = 0; r < 16; ++r) s0[r] *= SC2;
            }
            if (live1) {
                int kb1 = kb0 + 32;
                int khi1 = kb1 + 4 * hi;
                if (kb1 + 31 > q0w) {
#pragma unroll
                    for (int r = 0; r < 16; ++r) {
                        int kg = khi1 + ((r & 3) + 8 * (r >> 2));
                        s1[r] = (kg > qv) ? -1e30f : s1[r] * SC2;
                    }
                } else {
#pragma unroll
                    for (int r = 0; r < 16; ++r) s1[r] *= SC2;
                }
            }

            // --- merged row max over 32 values + hi-swap ---
            float m16[16];
#pragma unroll
            for (int r = 0; r < 16; ++r) m16[r] = fmaxf(s0[r], s1[r]);
            float m8[8], m4[4];
#pragma unroll
            for (int r = 0; r < 8; ++r) m8[r] = fmaxf(m16[r], m16[r + 8]);
#pragma unroll
            for (int r = 0; r < 4; ++r) m4[r] = fmaxf(m8[r], m8[r + 4]);
            float pm = fmaxf(fmaxf(m4[0], m4[1]), fmaxf(m4[2], m4[3]));
            pm = fmaxf(pm, __shfl_xor(pm, 32));

            // --- T13 defer-max ---
            int allok = __all(pm - mrow <= THR);
            float ef = 1.f;
            if (!allok) {
                float mn = fmaxf(mrow, pm);
                ef = exp2f(mrow - mn);
                mrow = mn;
            }
            // --- exp2 + merged row sum ---
#pragma unroll
            for (int r = 0; r < 16; ++r) s0[r] = exp2f(s0[r] - mrow);
#pragma unroll
            for (int r = 0; r < 16; ++r) s1[r] = exp2f(s1[r] - mrow);
            float a16[16];
#pragma unroll
            for (int r = 0; r < 16; ++r) a16[r] = s0[r] + s1[r];
            float a8[8], a4[4];
#pragma unroll
            for (int r = 0; r < 8; ++r) a8[r] = a16[r] + a16[r + 8];
#pragma unroll
            for (int r = 0; r < 4; ++r) a4[r] = a8[r] + a8[r + 4];
            float rsum = (a4[0] + a4[1]) + (a4[2] + a4[3]);
            rsum += __shfl_xor(rsum, 32);

            if (!allok) {
                lrow = lrow * ef + rsum;
                xbuf[w][l31] = ef;
#pragma unroll
                for (int rr = 0; rr < 4; ++rr) {
                    f32x4 efv = *(const f32x4*)&xbuf[w][rr * 8 + hi * 4];
#pragma unroll
                    for (int j = 0; j < 4; ++j) {
                        o0[rr * 4 + j] *= efv[j];
                        o1[rr * 4 + j] *= efv[j];
                    }
                }
            } else {
                lrow += rsum;
            }

            // --- P -> bf16 A-frags (both subtiles): pack + shfl + select ---
            s16x8 pa[2][2];
#pragma unroll
            for (int sub = 0; sub < 2; ++sub) {
                const f32x16& sv = sub ? s1 : s0;
                unsigned c0 = pk2(sv[0],  sv[1]),  c1 = pk2(sv[2],  sv[3]);
                unsigned c2 = pk2(sv[4],  sv[5]),  c3 = pk2(sv[6],  sv[7]);
                unsigned c4 = pk2(sv[8],  sv[9]),  c5 = pk2(sv[10], sv[11]);
                unsigned c6 = pk2(sv[12], sv[13]), c7 = pk2(sv[14], sv[15]);
                unsigned x0 = __shfl_xor((int)c0, 32), x1 = __shfl_xor((int)c1, 32);
                unsigned x2 = __shfl_xor((int)c2, 32), x3 = __shfl_xor((int)c3, 32);
                unsigned x4 = __shfl_xor((int)c4, 32), x5 = __shfl_xor((int)c5, 32);
                unsigned x6 = __shfl_xor((int)c6, 32), x7 = __shfl_xor((int)c7, 32);
                u32x4 w0 = { h ? x2 : c0, h ? x3 : c1, h ? c2 : x0, h ? c3 : x1 };
                u32x4 w1 = { h ? x6 : c4, h ? x7 : c5, h ? c6 : x4, h ? c7 : x5 };
                pa[sub][0] = __builtin_bit_cast(s16x8, w0);
                pa[sub][1] = __builtin_bit_cast(s16x8, w1);
            }

            // --- PV: O += P * V over 64 keys ---
            __builtin_amdgcn_s_setprio(1);
#pragma unroll
            for (int sub = 0; sub < 2; ++sub)
#pragma unroll
                for (int ks = 0; ks < 2; ++ks) {
                    s16x8 bv0 = *(const s16x8*)&Vts[cur][(l31) * PAD + sub * 32 + ks * 16 + hi * 8];
                    s16x8 bv1 = *(const s16x8*)&Vts[cur][(32 + l31) * PAD + sub * 32 + ks * 16 + hi * 8];
                    o0 = mfma32(pa[sub][ks], bv0, o0);
                    o1 = mfma32(pa[sub][ks], bv1, o1);
                }
            __builtin_amdgcn_s_setprio(0);
        }
        __syncthreads();
    }

    // ---- epilogue: divide by l, write O ----
    float il = 1.0f / lrow;
    xbuf[w][l31] = il;
    f32x4 ilv[4];
#pragma unroll
    for (int rr = 0; rr < 4; ++rr)
        ilv[rr] = *(const f32x4*)&xbuf[w][rr * 8 + hi * 4];
#pragma unroll
    for (int r = 0; r < 16; ++r) {
        int t = q0w + ((r & 3) + 8 * (r >> 2)) + 4 * hi;
        float sc = ilv[r >> 2][r & 3];
        long rbase = ((long)(bb * 2048 + t)) * 1024 + hh * 64;
        O[rbase + l31]      = f2bf(o0[r] * sc);
        O[rbase + 32 + l31] = f2bf(o1[r] * sc);
    }
}

// ---------------------------------------------------------------------------
extern "C" void kernel_launch(void* const* d_in, const int* in_sizes, int n_in,
                              void* d_out, int out_size, void* d_ws, size_t ws_size,
                              hipStream_t stream)
{
    const float* x      = (const float*)d_in[0];
    const float* wq     = (const float*)d_in[1];
    const float* wk     = (const float*)d_in[2];
    const float* wv     = (const float*)d_in[3];
    const float* w_proj = (const float*)d_in[4];
    const float* b_proj = (const float*)d_in[5];
    const float* w1     = (const float*)d_in[6];
    const float* b1     = (const float*)d_in[7];
    const float* w2     = (const float*)d_in[8];
    const float* b2     = (const float*)d_in[9];
    const float* ln1_g  = (const float*)d_in[10];
    const float* ln1_b  = (const float*)d_in[11];
    const float* ln2_g  = (const float*)d_in[12];
    const float* ln2_b  = (const float*)d_in[13];

    char* ws = (char*)d_ws;
    u16*   WQKVt = (u16*)(ws + 0);           // 3072x1024 bf16
    u16*   WPt   = (u16*)(ws + 6291456);     // 1024x1024
    u16*   W1t   = (u16*)(ws + 8388608);     // 4096x1024
    u16*   W2t   = (u16*)(ws + 16777216);    // 1024x4096
    u16*   H     = (u16*)(ws + 25165824);    // 8192x1024 (h, then h2)
    u16*   Qb    = (u16*)(ws + 41943040);    // [B,H,T,D]
    u16*   Kb    = (u16*)(ws + 58720256);    // [B,H,T,D]
    u16*   Vb    = (u16*)(ws + 75497472);    // [B,H,D,T]  (transposed)
    u16*   Ob    = (u16*)(ws + 92274688);    // [B,T,C]
    u16*   FF    = (u16*)(ws + 41943040);    // 8192x4096, overlaps Q..O
    float* X1    = (float*)(ws + 109051904); // 8192x1024 fp32
    float* out   = (float*)d_out;

    transpose_cvt<<<dim3(16, 1, 16), 256, 0, stream>>>(wq, WQKVt,           1024, 64, 65536, 65536);
    transpose_cvt<<<dim3(16, 1, 16), 256, 0, stream>>>(wk, WQKVt + 1048576, 1024, 64, 65536, 65536);
    transpose_cvt<<<dim3(16, 1, 16), 256, 0, stream>>>(wv, WQKVt + 2097152, 1024, 64, 65536, 65536);
    transpose_cvt<<<dim3(16, 16, 1), 256, 0, stream>>>(w_proj, WPt, 1024, 1024, 0, 0);
    transpose_cvt<<<dim3(16, 64, 1), 256, 0, stream>>>(w1, W1t, 1024, 4096, 0, 0);
    transpose_cvt<<<dim3(64, 16, 1), 256, 0, stream>>>(w2, W2t, 4096, 1024, 0, 0);

    ln_bf16<<<8192, 256, 0, stream>>>(x, ln1_g, ln1_b, H);

    gemm_bt<0><<<dim3(64, 24), 256, 0, stream>>>(H, WQKVt, 8192, 3072, 1024,
        nullptr, nullptr, nullptr, nullptr, Qb, Kb, Vb);

    attn_kernel<<<dim3(16, 16, 4), 256, 0, stream>>>(Qb, Kb, Vb, Ob);

    gemm_bt<1><<<dim3(64, 8), 256, 0, stream>>>(Ob, WPt, 8192, 1024, 1024,
        X1, nullptr, b_proj, x, nullptr, nullptr, nullptr);

    ln_bf16<<<8192, 256, 0, stream>>>(X1, ln2_g, ln2_b, H);

    gemm_bt<2><<<dim3(64, 32), 256, 0, stream>>>(H, W1t, 8192, 4096, 1024,
        nullptr, FF, b1, nullptr, nullptr, nullptr, nullptr);

    gemm_bt<1><<<dim3(64, 8), 256, 0, stream>>>(FF, W2t, 8192, 1024, 4096,
        out, nullptr, b2, X1, nullptr, nullptr, nullptr);
}

// Round 10
// 425.567 us; speedup vs baseline: 1.1915x; 1.1915x over previous
//
#include <hip/hip_runtime.h>

// ---------------------------------------------------------------------------
// TransformerBlock on MI355X (gfx950), bf16 MFMA internal compute.
// B=4 T=2048 C=1024 H=16 D=64 FF=4096. All fp32 I/O; bf16 internally.
//
// R9: flash split-K attention with balanced pairing.
//  - work unit = (q-tile qt, half-k-range s), load qt+1 tiles.
//  - block p: phase0 = (qt=p, s=0, tiles [0,p+1)),
//             phase1 = (qt=15-p, s=1, tiles [16-p, 32-2p))  -> 17 tiles/block.
//  - grid (16,16,4) = 1024 equal blocks = 4 blocks/CU (2x R5 concurrency,
//    half the per-block critical path).
//  - phases write unnormalized partials (O' bf16, m/l fp32) to dead ws
//    regions; attn_combine merges (standard flash split-K math).
//  - R5 inner loop (verified, 118us @ 2/CU) kept verbatim.
// GEMMs / LN unchanged (R5 config: 128^2 m97 GEMMs everywhere).
// ---------------------------------------------------------------------------

#define DEVI __device__ __forceinline__

typedef float  f32x4  __attribute__((ext_vector_type(4)));
typedef float  f32x16 __attribute__((ext_vector_type(16)));
typedef __bf16 bf16x8 __attribute__((ext_vector_type(8)));
typedef short  s16x8  __attribute__((ext_vector_type(8)));
typedef unsigned int u32x4 __attribute__((ext_vector_type(4)));
typedef unsigned short u16;

DEVI u16 f2bf(float f) {            // native RNE fp32->bf16
    return __builtin_bit_cast(u16, (__bf16)f);
}

DEVI float bf2f(u16 u) {
    unsigned v = (unsigned)u << 16;
    return __builtin_bit_cast(float, v);
}

DEVI unsigned pk2(float lo, float hi2) {    // {bf16(lo), bf16(hi2)} dword
    return (unsigned)f2bf(lo) | ((unsigned)f2bf(hi2) << 16);
}

DEVI void gload_lds16(const void* g, void* l) {
    __builtin_amdgcn_global_load_lds(
        (__attribute__((address_space(1))) void*)(g),
        (__attribute__((address_space(3))) void*)(l), 16, 0, 0);
}

DEVI f32x4 mfma16(s16x8 a, s16x8 b, f32x4 c) {
    return __builtin_amdgcn_mfma_f32_16x16x32_bf16(
        __builtin_bit_cast(bf16x8, a), __builtin_bit_cast(bf16x8, b), c, 0, 0, 0);
}

DEVI f32x16 mfma32(s16x8 a, s16x8 b, f32x16 c) {
    return __builtin_amdgcn_mfma_f32_32x32x16_bf16(
        __builtin_bit_cast(bf16x8, a), __builtin_bit_cast(bf16x8, b), c, 0, 0, 0);
}

// ---------------------------------------------------------------------------
// Tiled transpose + fp32->bf16: dst[n][k] = src[k][n].  64x64 tile, 256 thr.
// ---------------------------------------------------------------------------
__global__ __launch_bounds__(256) void transpose_cvt(
    const float* __restrict__ src, u16* __restrict__ dst,
    int K, int N, long srcStride, long dstStride)
{
    __shared__ float t[64][65];
    src += (long)blockIdx.z * srcStride;
    dst += (long)blockIdx.z * dstStride;
    int k0 = blockIdx.x * 64, n0 = blockIdx.y * 64;
    int tx = threadIdx.x & 63, ty = threadIdx.x >> 6;
#pragma unroll
    for (int i = 0; i < 16; ++i) {
        int r = ty * 16 + i;
        t[r][tx] = src[(long)(k0 + r) * N + n0 + tx];
    }
    __syncthreads();
#pragma unroll
    for (int i = 0; i < 16; ++i) {
        int r = ty * 16 + i;
        dst[(long)(n0 + r) * K + k0 + tx] = f2bf(t[tx][r]);
    }
}

// ---------------------------------------------------------------------------
// LayerNorm row (C=1024) -> bf16.  1 row / block, 256 threads, float4 loads.
// ---------------------------------------------------------------------------
__global__ __launch_bounds__(256) void ln_bf16(
    const float* __restrict__ x, const float* __restrict__ g,
    const float* __restrict__ b, u16* __restrict__ out)
{
    int row = blockIdx.x, tid = threadIdx.x;
    const float4 v = ((const float4*)(x + (long)row * 1024))[tid];
    float s = v.x + v.y + v.z + v.w;
    float q = v.x * v.x + v.y * v.y + v.z * v.z + v.w * v.w;
#pragma unroll
    for (int m = 1; m < 64; m <<= 1) { s += __shfl_xor(s, m); q += __shfl_xor(q, m); }
    __shared__ float red[8];
    int lane = tid & 63, w = tid >> 6;
    if (lane == 0) { red[w] = s; red[w + 4] = q; }
    __syncthreads();
    s = red[0] + red[1] + red[2] + red[3];
    q = red[4] + red[5] + red[6] + red[7];
    float mu  = s * (1.0f / 1024.0f);
    float var = q * (1.0f / 1024.0f) - mu * mu;
    float rs  = rsqrtf(var + 1e-5f);
    float4 gv = ((const float4*)g)[tid];
    float4 bv = ((const float4*)b)[tid];
    ushort4 o;
    o.x = f2bf((v.x - mu) * rs * gv.x + bv.x);
    o.y = f2bf((v.y - mu) * rs * gv.y + bv.y);
    o.z = f2bf((v.z - mu) * rs * gv.z + bv.z);
    o.w = f2bf((v.w - mu) * rs * gv.w + bv.w);
    ((ushort4*)(out + (long)row * 1024))[tid] = o;
}

// ---------------------------------------------------------------------------
// GEMM: C[M,N] = A[M,K] * B[K,N], A row-major bf16, Bt = B^T [N][K] bf16.
// 128x128 tile, BK=32, 4 waves (2x2), 4x4 16x16x32 MFMA frags per wave.
// EPI: 0 = QKV scatter (V transposed!), 1 = +bias +resid -> fp32,
//      2 = relu(+bias) -> bf16
// ---------------------------------------------------------------------------
template <int EPI>
__global__ __launch_bounds__(256, 3) void gemm_bt(
    const u16* __restrict__ A, const u16* __restrict__ Bt,
    int M, int N, int K,
    float* __restrict__ outF, u16* __restrict__ outB,
    const float* __restrict__ bias, const float* __restrict__ resid,
    u16* __restrict__ qd, u16* __restrict__ kd, u16* __restrict__ vd)
{
    __shared__ alignas(16) u16 As[128 * 32];
    __shared__ alignas(16) u16 Bs[128 * 32];
    int tid = threadIdx.x;
    int lane = tid & 63, w = tid >> 6;
    int wm = w & 1, wn = w >> 1;
    int l15 = lane & 15, l4 = lane >> 4;
    long m0 = (long)blockIdx.x * 128, n0 = (long)blockIdx.y * 128;
    const u16* Ag = A + m0 * K;
    const u16* Bg = Bt + n0 * K;
    int scol = (lane & 3) * 8;
    int srow0 = (w * 2 + 0) * 16 + (lane >> 2);
    int srow1 = (w * 2 + 1) * 16 + (lane >> 2);

    f32x4 acc[4][4] = {};

    for (int kt = 0; kt < K; kt += 32) {
        gload_lds16(Ag + (long)srow0 * K + kt + scol, &As[(w * 2 + 0) * 512]);
        gload_lds16(Ag + (long)srow1 * K + kt + scol, &As[(w * 2 + 1) * 512]);
        gload_lds16(Bg + (long)srow0 * K + kt + scol, &Bs[(w * 2 + 0) * 512]);
        gload_lds16(Bg + (long)srow1 * K + kt + scol, &Bs[(w * 2 + 1) * 512]);
        __syncthreads();
        s16x8 a[4], b[4];
#pragma unroll
        for (int m = 0; m < 4; ++m)
            a[m] = *(const s16x8*)&As[(wm * 64 + m * 16 + l15) * 32 + l4 * 8];
#pragma unroll
        for (int n = 0; n < 4; ++n)
            b[n] = *(const s16x8*)&Bs[(wn * 64 + n * 16 + l15) * 32 + l4 * 8];
#pragma unroll
        for (int m = 0; m < 4; ++m)
#pragma unroll
            for (int n = 0; n < 4; ++n)
                acc[m][n] = mfma16(a[m], b[n], acc[m][n]);
        __syncthreads();
    }

    long mbase = m0 + wm * 64;
    long nbase = n0 + wn * 64;
#pragma unroll
    for (int m = 0; m < 4; ++m)
#pragma unroll
        for (int n = 0; n < 4; ++n)
#pragma unroll
            for (int r = 0; r < 4; ++r) {
                long row = mbase + m * 16 + l4 * 4 + r;
                long col = nbase + n * 16 + l15;
                float val = acc[m][n][r];
                if constexpr (EPI == 0) {
                    int c = (int)col;
                    int which = c >> 10, hh = (c >> 6) & 15, dd = c & 63;
                    int bb = (int)(row >> 11), tt = (int)(row & 2047);
                    if (which == 2) {
                        vd[((long)(bb * 16 + hh) * 64 + dd) * 2048 + tt] = f2bf(val);
                    } else {
                        u16* dst = which == 0 ? qd : kd;
                        dst[((long)(bb * 16 + hh) * 2048 + tt) * 64 + dd] = f2bf(val);
                    }
                } else if constexpr (EPI == 1) {
                    outF[row * N + col] = val + bias[col] + resid[row * N + col];
                } else {
                    float t2 = val + bias[col];
                    outB[row * N + col] = f2bf(t2 > 0.f ? t2 : 0.f);
                }
            }
}

// ---------------------------------------------------------------------------
// Causal flash attention, split-K partials.  Block p = (qt=p, s=0) then
// (qt=15-p, s=1).  4 waves x 32 q rows.  R5 inner loop verbatim; only the
// k-range and the (unnormalized) partial epilogue differ.
// Partials: Op[s] bf16 [B*H*T][64]; ML[s][0/1][B*H*T] = m, l (fp32).
// ---------------------------------------------------------------------------
__global__ __launch_bounds__(256, 4) void attn_split(
    const u16* __restrict__ Q, const u16* __restrict__ K,
    const u16* __restrict__ Vt,
    u16* __restrict__ Op0, u16* __restrict__ Op1, float* __restrict__ ML)
{
    constexpr int PAD = 72;
    constexpr float SC2 = 0.125f * 1.44269504088896f;   // scale * log2(e)
    constexpr float THR = 11.5416f;                     // 8 * log2(e)
    __shared__ alignas(16) u16 Ks[2][64 * PAD];
    __shared__ alignas(16) u16 Vts[2][64 * PAD];
    __shared__ alignas(16) float xbuf[4][32];           // per-wave bounce
    int tid = threadIdx.x, lane = tid & 63, w = tid >> 6;
    int l31 = lane & 31, hi = lane >> 5;
    bool h = (hi != 0);
    int p = blockIdx.x, hh = blockIdx.y, bb = blockIdx.z;
    const long hbase = ((long)(bb * 16 + hh)) * 2048 * 64;
    const long rb = ((long)(bb * 16 + hh)) * 2048;      // partial row base

    int srow[2], scol8[2];
#pragma unroll
    for (int i = 0; i < 2; ++i) {
        int c = tid + 256 * i;
        srow[i] = c >> 3;
        scol8[i] = (c & 7) * 8;
    }

#pragma unroll 1
    for (int ph = 0; ph < 2; ++ph) {
        int qt  = ph == 0 ? p : 15 - p;
        int kt0 = ph == 0 ? 0 : (qt + 1);
        int kt1 = qt + 1 + ph * (qt + 1);   // ph0: qt+1, ph1: 2qt+2
        int ntl = kt1 - kt0;
        int q0w = qt * 128 + w * 32;
        int qv = q0w + l31;                 // this lane's q row

        // Q b-frags
        s16x8 bq[4];
#pragma unroll
        for (int c = 0; c < 4; ++c)
            bq[c] = *(const s16x8*)&Q[hbase + (long)(q0w + l31) * 64 + c * 16 + hi * 8];

        f32x16 o0 = {}, o1 = {};            // O'[q=crow][d=l31 | 32+l31]
        float mrow = -1e30f, lrow = 0.f;

        // ---- prologue: tile kt0 -> buf0 (direct), kt0+1 -> regs ----
        s16x8 kr[2], vr[2];
        {
            const u16* Kg = K + hbase + (long)kt0 * 64 * 64;
            const u16* Vg = Vt + hbase + (long)kt0 * 64;
#pragma unroll
            for (int i = 0; i < 2; ++i) {
                s16x8 k0 = *(const s16x8*)&Kg[srow[i] * 64 + scol8[i]];
                s16x8 v0 = *(const s16x8*)&Vg[(long)srow[i] * 2048 + scol8[i]];
                *(s16x8*)&Ks[0][srow[i] * PAD + scol8[i]]  = k0;
                *(s16x8*)&Vts[0][srow[i] * PAD + scol8[i]] = v0;
            }
            if (ntl > 1) {
                const u16* Kg1 = K + hbase + (long)(kt0 + 1) * 64 * 64;
                const u16* Vg1 = Vt + hbase + (long)(kt0 + 1) * 64;
#pragma unroll
                for (int i = 0; i < 2; ++i) {
                    kr[i] = *(const s16x8*)&Kg1[srow[i] * 64 + scol8[i]];
                    vr[i] = *(const s16x8*)&Vg1[(long)srow[i] * 2048 + scol8[i]];
                }
            }
        }
        __syncthreads();

#pragma unroll 1
        for (int j = 0; j < ntl; ++j) {
            int kt = kt0 + j;
            int cur = j & 1;
            if (j + 1 < ntl) {
#pragma unroll
                for (int i = 0; i < 2; ++i) {
                    *(s16x8*)&Ks[cur ^ 1][srow[i] * PAD + scol8[i]]  = kr[i];
                    *(s16x8*)&Vts[cur ^ 1][srow[i] * PAD + scol8[i]] = vr[i];
                }
            }
            if (j + 2 < ntl) {
                const u16* Kg = K + hbase + (long)(kt + 2) * 64 * 64;
                const u16* Vg = Vt + hbase + (long)(kt + 2) * 64;
#pragma unroll
                for (int i = 0; i < 2; ++i) {
                    kr[i] = *(const s16x8*)&Kg[srow[i] * 64 + scol8[i]];
                    vr[i] = *(const s16x8*)&Vg[(long)srow[i] * 2048 + scol8[i]];
                }
            }

#pragma unroll
            for (int k2 = 0; k2 < 2; ++k2) {
                int kbase = kt * 64 + k2 * 32;
                if (kbase <= q0w + 31) {    // else fully masked for this wave
                    f32x16 s = {};
                    __builtin_amdgcn_s_setprio(1);
#pragma unroll
                    for (int c = 0; c < 4; ++c) {
                        s16x8 ak = *(const s16x8*)&Ks[cur][(k2 * 32 + l31) * PAD + c * 16 + hi * 8];
                        s = mfma32(ak, bq[c], s);
                    }
                    __builtin_amdgcn_s_setprio(0);

                    int khi = kbase + 4 * hi;
                    if (kbase + 31 > q0w) {
#pragma unroll
                        for (int r = 0; r < 16; ++r) {
                            int kg = khi + ((r & 3) + 8 * (r >> 2));
                            float sv = s[r] * SC2;
                            s[r] = (kg > qv) ? -1e30f : sv;
                        }
                    } else {
#pragma unroll
                        for (int r = 0; r < 16; ++r) s[r] *= SC2;
                    }

                    float t8[8], t4[4], t2[2];
#pragma unroll
                    for (int r = 0; r < 8; ++r) t8[r] = fmaxf(s[r], s[r + 8]);
#pragma unroll
                    for (int r = 0; r < 4; ++r) t4[r] = fmaxf(t8[r], t8[r + 4]);
                    t2[0] = fmaxf(t4[0], t4[2]); t2[1] = fmaxf(t4[1], t4[3]);
                    float pm = fmaxf(t2[0], t2[1]);
                    pm = fmaxf(pm, __shfl_xor(pm, 32));

                    int allok = __all(pm - mrow <= THR);
                    float ef = 1.f;
                    if (!allok) {
                        float mn = fmaxf(mrow, pm);
                        ef = exp2f(mrow - mn);
                        mrow = mn;
                    }
                    float a8[8], a4[4];
#pragma unroll
                    for (int r = 0; r < 16; ++r) s[r] = exp2f(s[r] - mrow);
#pragma unroll
                    for (int r = 0; r < 8; ++r) a8[r] = s[r] + s[r + 8];
#pragma unroll
                    for (int r = 0; r < 4; ++r) a4[r] = a8[r] + a8[r + 4];
                    float rsum = (a4[0] + a4[1]) + (a4[2] + a4[3]);
                    rsum += __shfl_xor(rsum, 32);

                    if (!allok) {
                        lrow = lrow * ef + rsum;
                        xbuf[w][l31] = ef;
#pragma unroll
                        for (int rr = 0; rr < 4; ++rr) {
                            f32x4 efv = *(const f32x4*)&xbuf[w][rr * 8 + hi * 4];
#pragma unroll
                            for (int j2 = 0; j2 < 4; ++j2) {
                                o0[rr * 4 + j2] *= efv[j2];
                                o1[rr * 4 + j2] *= efv[j2];
                            }
                        }
                    } else {
                        lrow += rsum;
                    }

                    unsigned c0 = pk2(s[0],  s[1]),  c1 = pk2(s[2],  s[3]);
                    unsigned c2 = pk2(s[4],  s[5]),  c3 = pk2(s[6],  s[7]);
                    unsigned c4 = pk2(s[8],  s[9]),  c5 = pk2(s[10], s[11]);
                    unsigned c6 = pk2(s[12], s[13]), c7 = pk2(s[14], s[15]);
                    unsigned x0 = __shfl_xor((int)c0, 32), x1 = __shfl_xor((int)c1, 32);
                    unsigned x2 = __shfl_xor((int)c2, 32), x3 = __shfl_xor((int)c3, 32);
                    unsigned x4 = __shfl_xor((int)c4, 32), x5 = __shfl_xor((int)c5, 32);
                    unsigned x6 = __shfl_xor((int)c6, 32), x7 = __shfl_xor((int)c7, 32);
                    u32x4 w0 = { h ? x2 : c0, h ? x3 : c1, h ? c2 : x0, h ? c3 : x1 };
                    u32x4 w1 = { h ? x6 : c4, h ? x7 : c5, h ? c6 : x4, h ? c7 : x5 };
                    s16x8 pa0 = __builtin_bit_cast(s16x8, w0);
                    s16x8 pa1 = __builtin_bit_cast(s16x8, w1);

                    __builtin_amdgcn_s_setprio(1);
#pragma unroll
                    for (int ks = 0; ks < 2; ++ks) {
                        s16x8 pa = ks ? pa1 : pa0;
                        s16x8 bv0 = *(const s16x8*)&Vts[cur][(l31) * PAD + k2 * 32 + ks * 16 + hi * 8];
                        s16x8 bv1 = *(const s16x8*)&Vts[cur][(32 + l31) * PAD + k2 * 32 + ks * 16 + hi * 8];
                        o0 = mfma32(pa, bv0, o0);
                        o1 = mfma32(pa, bv1, o1);
                    }
                    __builtin_amdgcn_s_setprio(0);
                }
            }
            __syncthreads();
        }

        // ---- partial epilogue: unnormalized O', m, l ----
        u16* Ops = ph ? Op1 : Op0;
#pragma unroll
        for (int r = 0; r < 16; ++r) {
            int t = q0w + ((r & 3) + 8 * (r >> 2)) + 4 * hi;
            long ro = (rb + t) * 64;
            Ops[ro + l31]      = f2bf(o0[r]);
            Ops[ro + 32 + l31] = f2bf(o1[r]);
        }
        if (hi == 0) {
            long mrow_i = rb + q0w + l31;
            ML[ph * 262144 + mrow_i]          = mrow;
            ML[ph * 262144 + 131072 + mrow_i] = lrow;
        }
        __syncthreads();   // protect LDS before next phase's prologue writes
    }
}

// ---------------------------------------------------------------------------
// Split-K combine: O = (w1*O1' + w2*O2') / (w1*l1 + w2*l2), w_s = 2^(m_s-mm).
// 16 rows/block, 16 thr/row x 4 d.  Writes Ob [B,T,C] bf16.
// ---------------------------------------------------------------------------
__global__ __launch_bounds__(256) void attn_combine(
    const u16* __restrict__ Op0, const u16* __restrict__ Op1,
    const float* __restrict__ ML, u16* __restrict__ O)
{
    int tid = threadIdx.x;
    long row = (long)blockIdx.x * 16 + (tid >> 4);      // 0..131071
    int d0 = (tid & 15) * 4;
    float m1 = ML[row],          l1 = ML[131072 + row];
    float m2 = ML[262144 + row], l2 = ML[393216 + row];
    float mm = fmaxf(m1, m2);
    float w1 = exp2f(m1 - mm), w2 = exp2f(m2 - mm);
    float inv = 1.0f / (w1 * l1 + w2 * l2);
    ushort4 a = *(const ushort4*)&Op0[row * 64 + d0];
    ushort4 b = *(const ushort4*)&Op1[row * 64 + d0];
    ushort4 o;
    o.x = f2bf((w1 * bf2f(a.x) + w2 * bf2f(b.x)) * inv);
    o.y = f2bf((w1 * bf2f(a.y) + w2 * bf2f(b.y)) * inv);
    o.z = f2bf((w1 * bf2f(a.z) + w2 * bf2f(b.z)) * inv);
    o.w = f2bf((w1 * bf2f(a.w) + w2 * bf2f(b.w)) * inv);
    int bb = (int)(row >> 15), hh2 = (int)((row >> 11) & 15), t = (int)(row & 2047);
    *(ushort4*)&O[((long)(bb * 2048 + t)) * 1024 + hh2 * 64 + d0] = o;
}

// ---------------------------------------------------------------------------
extern "C" void kernel_launch(void* const* d_in, const int* in_sizes, int n_in,
                              void* d_out, int out_size, void* d_ws, size_t ws_size,
                              hipStream_t stream)
{
    const float* x      = (const float*)d_in[0];
    const float* wq     = (const float*)d_in[1];
    const float* wk     = (const float*)d_in[2];
    const float* wv     = (const float*)d_in[3];
    const float* w_proj = (const float*)d_in[4];
    const float* b_proj = (const float*)d_in[5];
    const float* w1     = (const float*)d_in[6];
    const float* b1     = (const float*)d_in[7];
    const float* w2     = (const float*)d_in[8];
    const float* b2     = (const float*)d_in[9];
    const float* ln1_g  = (const float*)d_in[10];
    const float* ln1_b  = (const float*)d_in[11];
    const float* ln2_g  = (const float*)d_in[12];
    const float* ln2_b  = (const float*)d_in[13];

    char* ws = (char*)d_ws;
    u16*   WQKVt = (u16*)(ws + 0);           // 3072x1024 bf16
    u16*   WPt   = (u16*)(ws + 6291456);     // 1024x1024
    u16*   W1t   = (u16*)(ws + 8388608);     // 4096x1024
    u16*   W2t   = (u16*)(ws + 16777216);    // 1024x4096
    u16*   H     = (u16*)(ws + 25165824);    // 8192x1024 (h, then h2)
    float* ML    = (float*)(ws + 25165824 + 8388608);  // 2MB (dead half of H region... no:
    // H is 16.77MB (25165824..41943040); LN output uses all of it.  ML must
    // NOT overlap H while H is dead?  H is dead during attn (consumed by QKV
    // GEMM), and LN2 rewrites it after combine.  ML lives only attn->combine,
    // H region is free then.  Place ML at H base.
    u16*   Qb    = (u16*)(ws + 41943040);    // [B,H,T,D]
    u16*   Kb    = (u16*)(ws + 58720256);    // [B,H,T,D]
    u16*   Vb    = (u16*)(ws + 75497472);    // [B,H,D,T]  (transposed)
    u16*   Ob    = (u16*)(ws + 92274688);    // [B,T,C]
    u16*   FF    = (u16*)(ws + 41943040);    // 8192x4096, overlaps Q..O
    float* X1    = (float*)(ws + 109051904); // 8192x1024 fp32
    u16*   Op0   = (u16*)(ws + 109051904);   // split partials overlap X1
    u16*   Op1   = (u16*)(ws + 109051904 + 16777216);
    float* out   = (float*)d_out;
    ML = (float*)(ws + 25165824);            // H region (dead during attn)

    transpose_cvt<<<dim3(16, 1, 16), 256, 0, stream>>>(wq, WQKVt,           1024, 64, 65536, 65536);
    transpose_cvt<<<dim3(16, 1, 16), 256, 0, stream>>>(wk, WQKVt + 1048576, 1024, 64, 65536, 65536);
    transpose_cvt<<<dim3(16, 1, 16), 256, 0, stream>>>(wv, WQKVt + 2097152, 1024, 64, 65536, 65536);
    transpose_cvt<<<dim3(16, 16, 1), 256, 0, stream>>>(w_proj, WPt, 1024, 1024, 0, 0);
    transpose_cvt<<<dim3(16, 64, 1), 256, 0, stream>>>(w1, W1t, 1024, 4096, 0, 0);
    transpose_cvt<<<dim3(64, 16, 1), 256, 0, stream>>>(w2, W2t, 4096, 1024, 0, 0);

    ln_bf16<<<8192, 256, 0, stream>>>(x, ln1_g, ln1_b, H);

    gemm_bt<0><<<dim3(64, 24), 256, 0, stream>>>(H, WQKVt, 8192, 3072, 1024,
        nullptr, nullptr, nullptr, nullptr, Qb, Kb, Vb);

    attn_split<<<dim3(16, 16, 4), 256, 0, stream>>>(Qb, Kb, Vb, Op0, Op1, ML);
    attn_combine<<<8192, 256, 0, stream>>>(Op0, Op1, ML, Ob);

    gemm_bt<1><<<dim3(64, 8), 256, 0, stream>>>(Ob, WPt, 8192, 1024, 1024,
        X1, nullptr, b_proj, x, nullptr, nullptr, nullptr);

    ln_bf16<<<8192, 256, 0, stream>>>(X1, ln2_g, ln2_b, H);

    gemm_bt<2><<<dim3(64, 32), 256, 0, stream>>>(H, W1t, 8192, 4096, 1024,
        nullptr, FF, b1, nullptr, nullptr, nullptr, nullptr);

    gemm_bt<1><<<dim3(64, 8), 256, 0, stream>>>(FF, W2t, 8192, 1024, 4096,
        out, nullptr, b2, X1, nullptr, nullptr, nullptr);
}